// Round 8
// baseline (297.177 us; speedup 1.0000x reference)
//
#include <hip/hip_runtime.h>
#include <hip/hip_fp16.h>

// patches_generator: bilinear grid_sample (border, align_corners=False)
// fm:   [N=16, C=128, H=112, W=112] f32
// grid: [N, P=98, 16, 16, 2] f32  (x,y) in [-1,1]
// out:  [N, P, C, 16, 16] f32
//
// Round-8: SINGLE-VARIABLE experiment vs r7 — plain (cached) output stores
// instead of __builtin_nontemporal_store. Everything else identical to r7.
// Rationale: r1..r7 invariance at ~98-110us kernel across LDS-instr/2,
// LDS-word/2, store-instr/4, VALU/2, tail-kill, and occupancy 24->16 waves
// (null!) exonerates compute, LDS, issue, and latency. The untouched
// constant is the nt write stream (205 MB): if nt caps write BW at ~2.5-3
// TB/s it is a ~75us serial floor masking every other change. Plain stores
// go through L2 write-combining (the 6.5 TB/s fill path). Grid evictions
// fall to L3 (grid is 6.4 MB total, L3-resident) — no added HBM fetch.

#define NN 16
#define CC 128
#define HH 112
#define WW 112
#define PP 98
#define PTS 256                  // 16x16 sample points per patch
#define NPTS (PP * PTS)          // 25088 points per batch image
#define NQUADS (NPTS / 4)        // 6272 point-quads
#define HWs (HH * WW)            // 12544 pixels; 4 B each (2x fp16) = 49 KB
#define PAD 113                  // pad row: border taps in-bounds, weight 0
#define THREADS 512

typedef float f32x4 __attribute__((ext_vector_type(4)));
typedef unsigned int u32x4 __attribute__((ext_vector_type(4)));

__device__ __forceinline__ unsigned int pack2(float a, float b) {
  __half2 h = __floats2half2_rn(a, b);   // v_cvt_pkrtz_f16_f32
  return *reinterpret_cast<unsigned int*>(&h);
}

// one bilinear sample from the fp16-packed pair plane -> (chanA, chanB)
__device__ __forceinline__ float2 samp(const unsigned int* __restrict__ plane,
                                       float gx, float gy) {
  const float x = fminf(fmaxf(fmaf(gx, (float)WW * 0.5f, (float)WW * 0.5f - 0.5f),
                              0.0f), (float)(WW - 1));
  const float y = fminf(fmaxf(fmaf(gy, (float)HH * 0.5f, (float)HH * 0.5f - 0.5f),
                              0.0f), (float)(HH - 1));
  const float x0f = floorf(x), y0f = floorf(y);
  const float wx = x - x0f, wy = y - y0f;
  // two ds_read2_b32; x1/y1 clamps unneeded (weight exactly 0 at border,
  // pad row keeps the reads in-bounds and finite)
  const unsigned int* p0 = reinterpret_cast<const unsigned int*>(
      reinterpret_cast<const char*>(plane) + ((int)y0f * WW + (int)x0f) * 4);
  const __half2 h00 = *reinterpret_cast<const __half2*>(&p0[0]);
  const __half2 h01 = *reinterpret_cast<const __half2*>(&p0[1]);
  const __half2 h10 = *reinterpret_cast<const __half2*>(&p0[WW]);
  const __half2 h11 = *reinterpret_cast<const __half2*>(&p0[WW + 1]);
  const float2 f00 = __half22float2(h00);
  const float2 f01 = __half22float2(h01);
  const float2 f10 = __half22float2(h10);
  const float2 f11 = __half22float2(h11);
  const float ux = 1.0f - wx, uy = 1.0f - wy;
  const float w00 = uy * ux, w01 = uy * wx, w10 = wy * ux, w11 = wy * wx;
  float2 r;
  r.x = fmaf(f11.x, w11, fmaf(f10.x, w10, fmaf(f01.x, w01, f00.x * w00)));
  r.y = fmaf(f11.y, w11, fmaf(f10.y, w10, fmaf(f01.y, w01, f00.y * w00)));
  return r;
}

__global__ __launch_bounds__(THREADS) void patches_kernel(
    const float* __restrict__ fm,
    const float* __restrict__ grid,
    float* __restrict__ out) {
  __shared__ unsigned int plane[HWs + PAD];

  const int n = blockIdx.y;
  const int t = threadIdx.x;
  const f32x4* __restrict__ g4 =
      reinterpret_cast<const f32x4*>(grid + (size_t)n * NPTS * 2);

  // two channel-pairs per block, sequentially (512 blocks = exactly 2/CU)
  for (int half = 0; half < 2; ++half) {
    const int cp = blockIdx.x * 2 + half;   // channel pair index
    const int c0 = cp * 2;                  // channels c0, c0+1

    if (half) __syncthreads();              // all compute on prev plane done

    // ---- stage both planes, nontemporal f32x4 loads, pack to fp16x2 ----
    const f32x4* __restrict__ srcA =
        reinterpret_cast<const f32x4*>(fm + ((size_t)n * CC + c0) * HWs);
    const f32x4* __restrict__ srcB =
        reinterpret_cast<const f32x4*>(fm + ((size_t)n * CC + c0 + 1) * HWs);
    u32x4* dst = reinterpret_cast<u32x4*>(plane);
    for (int i = t; i < HWs / 4; i += THREADS) {
      const f32x4 a = __builtin_nontemporal_load(&srcA[i]);
      const f32x4 b = __builtin_nontemporal_load(&srcB[i]);
      u32x4 q;
      q.x = pack2(a.x, b.x);
      q.y = pack2(a.y, b.y);
      q.z = pack2(a.z, b.z);
      q.w = pack2(a.w, b.w);
      dst[i] = q;                            // ds_write_b128, coalesced
    }
    if (t < PAD) plane[HWs + t] = 0u;        // zero pad row
    __syncthreads();

    // out base for (n, p=0, c0, s=0); channel c0+1 is +PTS floats
    float* __restrict__ obase = out + ((size_t)n * PP * CC + c0) * PTS;

    // 6272 quads / 512 threads = 12 full iters + 128-thread tail
#pragma unroll 2
    for (int it = 0; it < 13; ++it) {
      const int q = t + it * THREADS;
      if (q < NQUADS) {
        const f32x4 ga = g4[q * 2];          // points 4q, 4q+1
        const f32x4 gb = g4[q * 2 + 1];      // points 4q+2, 4q+3
        const float2 r0 = samp(plane, ga.x, ga.y);
        const float2 r1 = samp(plane, ga.z, ga.w);
        const float2 r2 = samp(plane, gb.x, gb.y);
        const float2 r3 = samp(plane, gb.z, gb.w);
        f32x4 vA, vB;
        vA.x = r0.x; vA.y = r1.x; vA.z = r2.x; vA.w = r3.x;
        vB.x = r0.y; vB.y = r1.y; vB.z = r2.y; vB.w = r3.y;
        const int p = q >> 6;                // patch
        const int s4 = (q & 63) * 4;         // first sample of the quad
        float* o = obase + (size_t)p * CC * PTS + s4;
        // PLAIN stores (the experiment): L2 write-combined path
        *reinterpret_cast<f32x4*>(o) = vA;
        *reinterpret_cast<f32x4*>(o + PTS) = vB;
      }
    }
  }
}

extern "C" void kernel_launch(void* const* d_in, const int* in_sizes, int n_in,
                              void* d_out, int out_size, void* d_ws, size_t ws_size,
                              hipStream_t stream) {
  const float* fm = (const float*)d_in[0];
  const float* grid = (const float*)d_in[1];
  float* out = (float*)d_out;

  dim3 grd(CC / 4, NN);   // 512 blocks: (n, two channel-pairs) each = 2/CU exact
  dim3 blk(THREADS);
  patches_kernel<<<grd, blk, 0, stream>>>(fm, grid, out);
}

// Round 9
// 293.057 us; speedup vs baseline: 1.0141x; 1.0141x over previous
//
#include <hip/hip_runtime.h>
#include <hip/hip_fp16.h>

// patches_generator: bilinear grid_sample (border, align_corners=False)
// fm:   [N=16, C=128, H=112, W=112] f32
// grid: [N, P=98, 16, 16, 2] f32  (x,y) in [-1,1]
// out:  [N, P, C, 16, 16] f32
//
// Round-9: software-pipelined staging (T14 split: load-early / write-late).
// r8 lesson: nt stores are FASTER than plain (plain costs +14us via L2
// write-allocate) -> reverted. Remaining theory: staging is phase-locked —
// co-resident blocks stage in lockstep, so HBM-read / LDS-gather / HBM-write
// phases alternate in bursts instead of flowing. Fix:
//  - 256 blocks (1/CU exact), 1024 threads (16 waves), XCD-swizzled so each
//    XCD's 2 batch-images keep their 400 KB grid slice in its private L2
//  - TWO fp16-packed channel-pair LDS buffers (2 x 50.6 KB); 4 pairs/block
//  - per pair: issue next pair's global loads to REGISTERS before compute,
//    pack+ds_write into the other buffer after compute, 1 barrier/pair ->
//    next-pair HBM reads hide under the whole compute+store phase

#define NN 16
#define CC 128
#define HH 112
#define WW 112
#define PP 98
#define PTS 256                  // 16x16 sample points per patch
#define NPTS (PP * PTS)          // 25088 points per batch image
#define NQUADS (NPTS / 4)        // 6272 point-quads
#define HWs (HH * WW)            // 12544 pixels; 4 B each (2x fp16)
#define HW4 (HWs / 4)            // 3136 f32x4 chunks per plane
#define PAD 113                  // pad row: border taps in-bounds, weight 0
#define THREADS 1024

typedef float f32x4 __attribute__((ext_vector_type(4)));
typedef unsigned int u32x4 __attribute__((ext_vector_type(4)));

__device__ __forceinline__ unsigned int pack2(float a, float b) {
  __half2 h = __floats2half2_rn(a, b);   // v_cvt_pkrtz_f16_f32
  return *reinterpret_cast<unsigned int*>(&h);
}

// one bilinear sample from the fp16-packed pair plane -> (chanA, chanB)
__device__ __forceinline__ float2 samp(const unsigned int* __restrict__ plane,
                                       float gx, float gy) {
  const float x = fminf(fmaxf(fmaf(gx, (float)WW * 0.5f, (float)WW * 0.5f - 0.5f),
                              0.0f), (float)(WW - 1));
  const float y = fminf(fmaxf(fmaf(gy, (float)HH * 0.5f, (float)HH * 0.5f - 0.5f),
                              0.0f), (float)(HH - 1));
  const float x0f = floorf(x), y0f = floorf(y);
  const float wx = x - x0f, wy = y - y0f;
  const unsigned int* p0 = reinterpret_cast<const unsigned int*>(
      reinterpret_cast<const char*>(plane) + ((int)y0f * WW + (int)x0f) * 4);
  const __half2 h00 = *reinterpret_cast<const __half2*>(&p0[0]);
  const __half2 h01 = *reinterpret_cast<const __half2*>(&p0[1]);
  const __half2 h10 = *reinterpret_cast<const __half2*>(&p0[WW]);
  const __half2 h11 = *reinterpret_cast<const __half2*>(&p0[WW + 1]);
  const float2 f00 = __half22float2(h00);
  const float2 f01 = __half22float2(h01);
  const float2 f10 = __half22float2(h10);
  const float2 f11 = __half22float2(h11);
  const float ux = 1.0f - wx, uy = 1.0f - wy;
  const float w00 = uy * ux, w01 = uy * wx, w10 = wy * ux, w11 = wy * wx;
  float2 r;
  r.x = fmaf(f11.x, w11, fmaf(f10.x, w10, fmaf(f01.x, w01, f00.x * w00)));
  r.y = fmaf(f11.y, w11, fmaf(f10.y, w10, fmaf(f01.y, w01, f00.y * w00)));
  return r;
}

__global__ __launch_bounds__(THREADS, 4) void patches_kernel(
    const float* __restrict__ fm,
    const float* __restrict__ grid,
    float* __restrict__ out) {
  __shared__ unsigned int lbuf[2][HWs + PAD];   // 2 x 50.6 KB

  const int b = blockIdx.x;        // 0..255, one block per CU
  const int xcd = b & 7;           // dispatch round-robins XCDs
  const int idx = b >> 3;          // 0..31 within XCD
  const int n = (xcd << 1) | (idx >> 4);   // XCD k owns n = 2k, 2k+1
  const int cpb = (idx & 15) * 4;  // first of this block's 4 channel-pairs
  const int t = threadIdx.x;

  const f32x4* __restrict__ g4 =
      reinterpret_cast<const f32x4*>(grid + (size_t)n * NPTS * 2);

  if (t < PAD) { lbuf[0][HWs + t] = 0u; lbuf[1][HWs + t] = 0u; }

  // staging registers: 2 planes x (3 full + 1 guarded) f32x4 chunks
  f32x4 ra0, ra1, ra2, ra3, rb0, rb1, rb2, rb3;

  auto stage_load = [&](int j) {
    const f32x4* __restrict__ sA = reinterpret_cast<const f32x4*>(
        fm + ((size_t)n * CC + (size_t)(cpb + j) * 2) * HWs);
    const f32x4* __restrict__ sB = sA + HW4;
    ra0 = __builtin_nontemporal_load(&sA[t]);
    ra1 = __builtin_nontemporal_load(&sA[t + 1024]);
    ra2 = __builtin_nontemporal_load(&sA[t + 2048]);
    rb0 = __builtin_nontemporal_load(&sB[t]);
    rb1 = __builtin_nontemporal_load(&sB[t + 1024]);
    rb2 = __builtin_nontemporal_load(&sB[t + 2048]);
    if (t < HW4 - 3072) {   // 64 threads, wave-aligned
      ra3 = __builtin_nontemporal_load(&sA[t + 3072]);
      rb3 = __builtin_nontemporal_load(&sB[t + 3072]);
    }
  };

  auto stage_write = [&](unsigned int* d) {
    u32x4* dst = reinterpret_cast<u32x4*>(d);
    u32x4 q;
    q.x = pack2(ra0.x, rb0.x); q.y = pack2(ra0.y, rb0.y);
    q.z = pack2(ra0.z, rb0.z); q.w = pack2(ra0.w, rb0.w);
    dst[t] = q;
    q.x = pack2(ra1.x, rb1.x); q.y = pack2(ra1.y, rb1.y);
    q.z = pack2(ra1.z, rb1.z); q.w = pack2(ra1.w, rb1.w);
    dst[t + 1024] = q;
    q.x = pack2(ra2.x, rb2.x); q.y = pack2(ra2.y, rb2.y);
    q.z = pack2(ra2.z, rb2.z); q.w = pack2(ra2.w, rb2.w);
    dst[t + 2048] = q;
    if (t < HW4 - 3072) {
      q.x = pack2(ra3.x, rb3.x); q.y = pack2(ra3.y, rb3.y);
      q.z = pack2(ra3.z, rb3.z); q.w = pack2(ra3.w, rb3.w);
      dst[t + 3072] = q;
    }
  };

  auto compute = [&](int j, const unsigned int* __restrict__ pl) {
    float* __restrict__ obase =
        out + ((size_t)n * PP * CC + (size_t)(cpb + j) * 2) * PTS;
#pragma unroll 2
    for (int it = 0; it < 7; ++it) {   // 6272 quads / 1024 threads
      const int q = t + it * 1024;
      if (q < NQUADS) {
        const f32x4 ga = g4[q * 2];      // points 4q, 4q+1
        const f32x4 gb = g4[q * 2 + 1];  // points 4q+2, 4q+3
        const float2 r0 = samp(pl, ga.x, ga.y);
        const float2 r1 = samp(pl, ga.z, ga.w);
        const float2 r2 = samp(pl, gb.x, gb.y);
        const float2 r3 = samp(pl, gb.z, gb.w);
        f32x4 vA, vB;
        vA.x = r0.x; vA.y = r1.x; vA.z = r2.x; vA.w = r3.x;
        vB.x = r0.y; vB.y = r1.y; vB.z = r2.y; vB.w = r3.y;
        const int p = q >> 6;            // patch
        const int s4 = (q & 63) * 4;     // first sample of the quad
        float* o = obase + (size_t)p * CC * PTS + s4;
        __builtin_nontemporal_store(vA, reinterpret_cast<f32x4*>(o));
        __builtin_nontemporal_store(vB, reinterpret_cast<f32x4*>(o + PTS));
      }
    }
  };

  // ---- pipeline: load(j+1) early, compute(j), write(j+1) late ----
  stage_load(0);
  stage_write(lbuf[0]);    // compiler inserts vmcnt waits before reg uses
  __syncthreads();
#pragma unroll 1
  for (int j = 0; j < 4; ++j) {
    if (j < 3) stage_load(j + 1);      // HBM reads in flight under compute
    compute(j, lbuf[j & 1]);
    if (j < 3) stage_write(lbuf[(j + 1) & 1]);  // other buffer: no race
    __syncthreads();
  }
}

extern "C" void kernel_launch(void* const* d_in, const int* in_sizes, int n_in,
                              void* d_out, int out_size, void* d_ws, size_t ws_size,
                              hipStream_t stream) {
  const float* fm = (const float*)d_in[0];
  const float* grid = (const float*)d_in[1];
  float* out = (float*)d_out;

  dim3 grd(256);          // exactly 1 block per CU
  dim3 blk(THREADS);
  patches_kernel<<<grd, blk, 0, stream>>>(fm, grid, out);
}

// Round 10
// 288.166 us; speedup vs baseline: 1.0313x; 1.0170x over previous
//
#include <hip/hip_runtime.h>
#include <hip/hip_fp16.h>

// patches_generator: bilinear grid_sample (border, align_corners=False)
// fm:   [N=16, C=128, H=112, W=112] f32
// grid: [N, P=98, 16, 16, 2] f32  (x,y) in [-1,1]
// out:  [N, P, C, 16, 16] f32
//
// Round-10 = r7 (best: 283) + register-prefetch of the 2nd channel-pair
// (T14 issue-early/write-late), single-variable vs r7 apart from the XCD
// swizzle. r9's null is attributed to its confounds (1 block/CU, serial
// prologue); here occupancy/structure stay r7-identical (512 blocks x 512
// thr, 2 ch-pairs/block, one 50.6 KB LDS buffer, nt loads + nt stores).
// The 2nd pair's fm loads are issued into 56 VGPRs right after the 1st
// pair's LDS write -> the mid-kernel HBM read burst vanishes; reads drain
// under compute0's ~35us of LDS-gather + nt-writes. sched_barrier(0) pins
// the issue point so the compiler can't sink the loads to their use.

#define NN 16
#define CC 128
#define HH 112
#define WW 112
#define PP 98
#define PTS 256                  // 16x16 sample points per patch
#define NPTS (PP * PTS)          // 25088 points per batch image
#define NQUADS (NPTS / 4)        // 6272 point-quads
#define HWs (HH * WW)            // 12544 pixels; 4 B each (2x fp16)
#define HW4 (HWs / 4)            // 3136 f32x4 chunks per plane
#define PAD 113                  // pad row: border taps in-bounds, weight 0
#define THREADS 512
#define CHUNKS 6                 // 6*512=3072 full chunks; 64-chunk tail

typedef float f32x4 __attribute__((ext_vector_type(4)));
typedef unsigned int u32x4 __attribute__((ext_vector_type(4)));

__device__ __forceinline__ unsigned int pack2(float a, float b) {
  __half2 h = __floats2half2_rn(a, b);   // v_cvt_pkrtz_f16_f32
  return *reinterpret_cast<unsigned int*>(&h);
}

// one bilinear sample from the fp16-packed pair plane -> (chanA, chanB)
__device__ __forceinline__ float2 samp(const unsigned int* __restrict__ plane,
                                       float gx, float gy) {
  const float x = fminf(fmaxf(fmaf(gx, (float)WW * 0.5f, (float)WW * 0.5f - 0.5f),
                              0.0f), (float)(WW - 1));
  const float y = fminf(fmaxf(fmaf(gy, (float)HH * 0.5f, (float)HH * 0.5f - 0.5f),
                              0.0f), (float)(HH - 1));
  const float x0f = floorf(x), y0f = floorf(y);
  const float wx = x - x0f, wy = y - y0f;
  // two ds_read2_b32; x1/y1 clamps unneeded (weight exactly 0 at border,
  // pad row keeps reads in-bounds and finite)
  const unsigned int* p0 = reinterpret_cast<const unsigned int*>(
      reinterpret_cast<const char*>(plane) + ((int)y0f * WW + (int)x0f) * 4);
  const __half2 h00 = *reinterpret_cast<const __half2*>(&p0[0]);
  const __half2 h01 = *reinterpret_cast<const __half2*>(&p0[1]);
  const __half2 h10 = *reinterpret_cast<const __half2*>(&p0[WW]);
  const __half2 h11 = *reinterpret_cast<const __half2*>(&p0[WW + 1]);
  const float2 f00 = __half22float2(h00);
  const float2 f01 = __half22float2(h01);
  const float2 f10 = __half22float2(h10);
  const float2 f11 = __half22float2(h11);
  const float ux = 1.0f - wx, uy = 1.0f - wy;
  const float w00 = uy * ux, w01 = uy * wx, w10 = wy * ux, w11 = wy * wx;
  float2 r;
  r.x = fmaf(f11.x, w11, fmaf(f10.x, w10, fmaf(f01.x, w01, f00.x * w00)));
  r.y = fmaf(f11.y, w11, fmaf(f10.y, w10, fmaf(f01.y, w01, f00.y * w00)));
  return r;
}

__global__ __launch_bounds__(THREADS) void patches_kernel(
    const float* __restrict__ fm,
    const float* __restrict__ grid,
    float* __restrict__ out) {
  __shared__ unsigned int plane[HWs + PAD];

  // XCD swizzle: 512 blocks, XCD = b%8 owns 64 blocks = 2 full batch-images
  // -> each XCD's 2x200 KB grid slice stays in its private L2.
  const int b = blockIdx.x;
  const int xcd = b & 7;
  const int i = b >> 3;              // 0..63 within XCD
  const int n = xcd * 2 + (i >> 5);  // XCD k owns n = 2k, 2k+1
  const int cpg = i & 31;            // this block's channel-pair group
  const int t = threadIdx.x;

  const f32x4* __restrict__ g4 =
      reinterpret_cast<const f32x4*>(grid + (size_t)n * NPTS * 2);

  // prefetch registers for one channel-pair (2 planes): 14 x f32x4
  f32x4 ra[CHUNKS + 1], rb[CHUNKS + 1];

  auto load_pair = [&](int cp) {
    const f32x4* __restrict__ sA = reinterpret_cast<const f32x4*>(
        fm + ((size_t)n * CC + (size_t)cp * 2) * HWs);
    const f32x4* __restrict__ sB = sA + HW4;
#pragma unroll
    for (int k = 0; k < CHUNKS; ++k) {
      ra[k] = __builtin_nontemporal_load(&sA[t + k * THREADS]);
      rb[k] = __builtin_nontemporal_load(&sB[t + k * THREADS]);
    }
    if (t < HW4 - CHUNKS * THREADS) {   // 64 threads, wave-aligned
      ra[CHUNKS] = __builtin_nontemporal_load(&sA[t + CHUNKS * THREADS]);
      rb[CHUNKS] = __builtin_nontemporal_load(&sB[t + CHUNKS * THREADS]);
    }
  };

  auto write_pair = [&]() {
    u32x4* dst = reinterpret_cast<u32x4*>(plane);
#pragma unroll
    for (int k = 0; k < CHUNKS; ++k) {
      u32x4 q;
      q.x = pack2(ra[k].x, rb[k].x);
      q.y = pack2(ra[k].y, rb[k].y);
      q.z = pack2(ra[k].z, rb[k].z);
      q.w = pack2(ra[k].w, rb[k].w);
      dst[t + k * THREADS] = q;          // ds_write_b128, coalesced
    }
    if (t < HW4 - CHUNKS * THREADS) {
      u32x4 q;
      q.x = pack2(ra[CHUNKS].x, rb[CHUNKS].x);
      q.y = pack2(ra[CHUNKS].y, rb[CHUNKS].y);
      q.z = pack2(ra[CHUNKS].z, rb[CHUNKS].z);
      q.w = pack2(ra[CHUNKS].w, rb[CHUNKS].w);
      dst[t + CHUNKS * THREADS] = q;
    }
  };

  auto compute = [&](int cp) {
    float* __restrict__ obase =
        out + ((size_t)n * PP * CC + (size_t)cp * 2) * PTS;
#pragma unroll 2
    for (int it = 0; it < 13; ++it) {    // 6272 quads / 512 threads
      const int q = t + it * THREADS;
      if (q < NQUADS) {
        const f32x4 ga = g4[q * 2];      // points 4q, 4q+1
        const f32x4 gb = g4[q * 2 + 1];  // points 4q+2, 4q+3
        const float2 r0 = samp(plane, ga.x, ga.y);
        const float2 r1 = samp(plane, ga.z, ga.w);
        const float2 r2 = samp(plane, gb.x, gb.y);
        const float2 r3 = samp(plane, gb.z, gb.w);
        f32x4 vA, vB;
        vA.x = r0.x; vA.y = r1.x; vA.z = r2.x; vA.w = r3.x;
        vB.x = r0.y; vB.y = r1.y; vB.z = r2.y; vB.w = r3.y;
        const int p = q >> 6;            // patch
        const int s4 = (q & 63) * 4;     // first sample of the quad
        float* o = obase + (size_t)p * CC * PTS + s4;
        __builtin_nontemporal_store(vA, reinterpret_cast<f32x4*>(o));
        __builtin_nontemporal_store(vB, reinterpret_cast<f32x4*>(o + PTS));
      }
    }
  };

  const int cp0 = cpg * 2, cp1 = cpg * 2 + 1;

  // ---- pipeline ----
  load_pair(cp0);
  if (t < PAD) plane[HWs + t] = 0u;      // pad row stays 0 across both halves
  write_pair();                          // vmcnt waits on cp0 loads
  load_pair(cp1);                        // cp1 reads in flight under compute0
  __builtin_amdgcn_sched_barrier(0);     // pin issue point (no sinking)
  __syncthreads();
  compute(cp0);
  __syncthreads();                       // all lanes done reading plane
  write_pair();                          // cp1 regs -> LDS (loads long done)
  __syncthreads();
  compute(cp1);
}

extern "C" void kernel_launch(void* const* d_in, const int* in_sizes, int n_in,
                              void* d_out, int out_size, void* d_ws, size_t ws_size,
                              hipStream_t stream) {
  const float* fm = (const float*)d_in[0];
  const float* grid = (const float*)d_in[1];
  float* out = (float*)d_out;

  dim3 grd(512);          // 64 blocks per XCD = 2 batch-images each
  dim3 blk(THREADS);
  patches_kernel<<<grd, blk, 0, stream>>>(fm, grid, out);
}